// Round 3
// baseline (1561.275 us; speedup 1.0000x reference)
//
#include <hip/hip_runtime.h>

#define DTC 0.01f
#define LAM  2.88539008178f     // 2/ln2
#define L2E  1.44269504089f     // 1/ln2

typedef __attribute__((ext_vector_type(8))) short short8;
typedef __attribute__((ext_vector_type(4))) float floatx4;

#if __has_builtin(__builtin_amdgcn_exp2f)
#define EXP2F(x) __builtin_amdgcn_exp2f(x)
#else
#define EXP2F(x) exp2f(x)
#endif
#if __has_builtin(__builtin_amdgcn_rcpf)
#define RCPF(x) __builtin_amdgcn_rcpf(x)
#else
#define RCPF(x) (1.0f / (x))
#endif

__device__ __forceinline__ unsigned short f2bf(float f) {
    unsigned u = __float_as_uint(f);
    u += 0x7FFFu + ((u >> 16) & 1u);
    return (unsigned short)(u >> 16);
}
// 1/(1+2^y): with gate pre-activations pre-scaled by -1/ln2 this IS sigmoid;
// with +2/ln2 scaling, tanh = 1 - 2*rcp1p.
__device__ __forceinline__ float rcp1p(float y) {
    return RCPF(1.0f + EXP2F(y));
}
// Raw barrier: drains LDS ops for cross-wave visibility but NOT vmcnt, so
// wave0's out/res global stores stay in flight across barriers.
__device__ __forceinline__ void wg_barrier() {
    asm volatile("s_waitcnt lgkmcnt(0)" ::: "memory");
    __builtin_amdgcn_s_barrier();
}
// r[l<32] = lo[l]; r[l>=32] = hi[l-32]   (v_permlane32_swap_b32 vdst=lo, vsrc=hi)
__device__ __forceinline__ float lane_merge(float lo, float hi) {
#if __has_builtin(__builtin_amdgcn_permlane32_swap)
    typedef __attribute__((ext_vector_type(2))) unsigned int uint2v;
    uint2v r = __builtin_amdgcn_permlane32_swap(__float_as_uint(lo), __float_as_uint(hi),
                                                false, false);
    return __uint_as_float(r[0]);
#else
    unsigned a = __float_as_uint(lo), b = __float_as_uint(hi);
    asm volatile("v_permlane32_swap_b32 %0, %1" : "+v"(a), "+v"(b));
    return __uint_as_float(a);
#endif
}

#define U1S 136   // bf16 elements; byte stride 272 = 16*17 -> spread b128 reads

#define MFMA(a, b, c) __builtin_amdgcn_mfma_f32_16x16x32_bf16((a), (b), (c), 0, 0, 0)

// 8 batch rows per block, grid = B/8 = 512 -> 2 independent blocks per CU
// (independent barrier domains overlap each other's stalls). MFMA stays 16x16
// with rows 8..15 zero-padded; after the gate MFMAs the 8 real C-frag rows are
// compacted onto all 64 lanes via v_permlane32_swap_b32 so the transcendental
// work is 2 elements/thread/cell -> per-SIMD trans issue stays at the 16-row
// invariant while every structural stall gains a hiding partner.
__global__ __launch_bounds__(256, 2) void lstm_mfma(
    const float* __restrict__ x,    const float* __restrict__ s0,
    const float* __restrict__ W_ih0,const float* __restrict__ W_hh0,
    const float* __restrict__ b_ih0,const float* __restrict__ b_hh0,
    const float* __restrict__ W_ih1,const float* __restrict__ W_hh1,
    const float* __restrict__ b_ih1,const float* __restrict__ b_hh1,
    const float* __restrict__ fc_W, const float* __restrict__ fc_b,
    const int* __restrict__ nsp,    float* __restrict__ out, int B)
{
    // U1: [16 rows m][cols: 0..63 = h_a(t) bf16, 64..127 = h_b(t) bf16]
    // rows 8..15 stay zero (padding).
    __shared__ __align__(16) unsigned short U1[16 * U1S];

    const int ns   = nsp[0];
    const int tid  = threadIdx.x;
    const int lane = tid & 63;
    const int wave = tid >> 6;        // 0..3
    const int il   = lane & 15;
    const int quad = lane >> 4;
    const int bb   = blockIdx.x * 8;  // 8 batch rows per block

    float* cal = out + (size_t)B * ns * 8;
    float* res = cal + ns;

    if (blockIdx.x == 0)
        for (int t = tid; t < ns; t += 256) cal[t] = t * DTC;

    for (int i = tid; i < 16 * U1S; i += 256) U1[i] = 0;

    // ---- register-resident B-fragments (constant over time) ----
    // Wave w owns gate cols n = 64j + 16w + il. Gate pre-scale folded into
    // bf16 weights: gamma = -1/ln2 (sigmoid gates i,f,o), +2/ln2 (tanh gate g).
    // Cell state carried LAM-scaled. s removed from the MFMA path: gs[j]
    // carries gamma*(b0 + W_x*x + W_s*s(t)) in fp32, updated each step via
    // gs += MFMA(h_b(t-1), gamma*DT*(W_s@fc_W)) + gd  (exact, s is affine).
    short8 B0[4][2], B1[4][4], M2f[4][2], BF[2];
    floatx4 gs[4];
    float gd[4], b1s[4];

    for (int j = 0; j < 4; ++j) {
        const float gam = (j == 2) ? LAM : -L2E;
        const int n = 64 * j + 16 * wave + il;
        float ws[8];
        #pragma unroll
        for (int p = 0; p < 8; ++p) ws[p] = W_ih0[n * 16 + 8 + p];

        #pragma unroll
        for (int kk = 0; kk < 2; ++kk) {        // G0: K = h_a(64)
            short8 f;
            #pragma unroll
            for (int jj = 0; jj < 8; ++jj) {
                int k = 32 * kk + 8 * quad + jj;
                f[jj] = (short)f2bf(gam * W_hh0[n * 64 + k]);
            }
            B0[j][kk] = f;
        }
        #pragma unroll
        for (int kk = 0; kk < 4; ++kk) {        // G1: K = [h_a(64) | h_b(64)]
            short8 f;
            #pragma unroll
            for (int jj = 0; jj < 8; ++jj) {
                int k = 32 * kk + 8 * quad + jj;
                float w = (k < 64) ? W_ih1[n * 64 + k] : W_hh1[n * 64 + (k - 64)];
                f[jj] = (short)f2bf(gam * w);
            }
            B1[j][kk] = f;
        }
        #pragma unroll
        for (int kk = 0; kk < 2; ++kk) {        // M2 = W_s @ fc_W
            short8 f;
            #pragma unroll
            for (int jj = 0; jj < 8; ++jj) {
                int k = 32 * kk + 8 * quad + jj;
                float acc = 0.0f;
                #pragma unroll
                for (int p = 0; p < 8; ++p) acc += ws[p] * fc_W[p * 64 + k];
                f[jj] = (short)f2bf(gam * DTC * acc);
            }
            M2f[j][kk] = f;
        }
        float accb = 0.0f;
        #pragma unroll
        for (int p = 0; p < 8; ++p) accb += ws[p] * fc_b[p];
        gd[j] = gam * DTC * accb;

        float bcol = b_ih0[n] + b_hh0[n];
        floatx4 gv;
        #pragma unroll
        for (int reg = 0; reg < 4; ++reg) {
            int m  = 4 * quad + reg;
            int mr = bb + (m & 7);              // clamp padding rows in-bounds
            float acc = bcol;
            #pragma unroll
            for (int k = 0; k < 8; ++k) acc += x[mr * 8 + k] * W_ih0[n * 16 + k];
            #pragma unroll
            for (int p = 0; p < 8; ++p) acc += ws[p] * s0[mr * 8 + p];
            gv[reg] = gam * acc - gd[j];        // t=0 update adds gd back
        }
        gs[j] = gv;
        b1s[j] = gam * (b_ih1[n] + b_hh1[n]);
    }
    #pragma unroll
    for (int kk = 0; kk < 2; ++kk) {            // FC head (wave0 uses it)
        short8 f;
        #pragma unroll
        for (int jj = 0; jj < 8; ++jj) {
            int k = 32 * kk + 8 * quad + jj;
            float w = (il < 8) ? fc_W[il * 64 + k] : 0.0f;
            f[jj] = (short)f2bf(w);
        }
        BF[kk] = f;
    }
    const float fcb = (il < 8) ? fc_b[il] : 0.0f;

    // ---- state ----
    // After compaction, this lane owns cell elements (m = mbase+e, col iidx):
    const int mbase = 4 * ((lane & 31) >> 4) + ((lane >> 5) << 1);
    const int iidx  = 16 * wave + il;
    float cA[2] = {0, 0}, cB[2] = {0, 0};       // LAM-scaled cell states
    float s_reg[4];
    #pragma unroll
    for (int reg = 0; reg < 4; ++reg) {
        int m = 4 * quad + reg;
        s_reg[reg] = (il < 8 && m < 8) ? s0[(bb + m) * 8 + il] : 0.0f;
    }

    short8 a10 = {0,0,0,0,0,0,0,0};             // h_a(t-1) carried in registers
    short8 a11 = {0,0,0,0,0,0,0,0};

    const unsigned short* Ar = &U1[il * U1S + 8 * quad];   // A-frag reads
    unsigned short* Hw = &U1[mbase * U1S + iidx];          // compacted h writes

    wg_barrier();

    // 2 barriers/step (as R1): B (h_a ready), C (h_b ready).
    #pragma unroll 1
    for (int t = 0; t < ns; ++t) {
        // ---- phase 1: cell0 gates + layer-1 partials ----
        short8 a12 = *(const short8*)(Ar + 64);   // h_b(t-1)
        short8 a13 = *(const short8*)(Ar + 96);

        floatx4 q0[4], p1[4];
        #pragma unroll
        for (int j = 0; j < 4; ++j) {
            floatx4 z = gs[j];                    // affine s-path update
            z = MFMA(a12, M2f[j][0], z);
            z = MFMA(a13, M2f[j][1], z);
            #pragma unroll
            for (int r = 0; r < 4; ++r) z[r] += gd[j];
            gs[j] = z;
            floatx4 q = z;                        // preact0 = gs(t) + B0*h_a(t-1)
            q = MFMA(a10, B0[j][0], q);
            q = MFMA(a11, B0[j][1], q);
            q0[j] = q;
            floatx4 pz = {b1s[j], b1s[j], b1s[j], b1s[j]};
            pz = MFMA(a13, B1[j][3], pz);         // layer-1 h_b partial
            pz = MFMA(a12, B1[j][2], pz);
            p1[j] = pz;
        }
        // compact 8 real rows onto 64 lanes: P[e][j], e=0 -> m=mbase, e=1 -> m=mbase+1
        float P[2][4];
        #pragma unroll
        for (int j = 0; j < 4; ++j) {
            P[0][j] = lane_merge(q0[j][0], q0[j][2]);
            P[1][j] = lane_merge(q0[j][1], q0[j][3]);
        }
        #pragma unroll
        for (int e = 0; e < 2; ++e) {             // cell 0
            float iv = rcp1p(P[e][0]);
            float fv = rcp1p(P[e][1]);
            float gr = rcp1p(P[e][2]);
            float ov = rcp1p(P[e][3]);
            float gl = __builtin_fmaf(gr, -2.0f * LAM, LAM);   // LAM*tanh(g)
            float c  = __builtin_fmaf(fv, cA[e], iv * gl);
            cA[e]    = c;
            float r2 = rcp1p(c);
            float h  = __builtin_fmaf(-2.0f, ov * r2, ov);
            Hw[e * U1S] = f2bf(h);                // h_a(t)
        }
        wg_barrier();   // B

        // ---- phase 2: cell1 gates ----
        a10 = *(const short8*)(Ar + 0);           // h_a(t), reused next iter
        a11 = *(const short8*)(Ar + 32);

        if (t && wave == 0) {                     // deferred FC(t-1)
            floatx4 so = {fcb, fcb, fcb, fcb};
            so = MFMA(a12, BF[0], so);
            so = MFMA(a13, BF[1], so);
            #pragma unroll
            for (int reg = 0; reg < 4; ++reg) {
                s_reg[reg] += so[reg] * DTC;
                if (quad < 2 && il < 8) {
                    size_t o = ((size_t)(bb + 4 * quad + reg) * ns + (t - 1)) * 8 + il;
                    out[o] = s_reg[reg];
                    res[o] = so[reg];
                }
            }
        }

        floatx4 q1[4];
        #pragma unroll
        for (int j = 0; j < 4; ++j) {
            floatx4 z = p1[j];
            z = MFMA(a10, B1[j][0], z);
            z = MFMA(a11, B1[j][1], z);
            q1[j] = z;
        }
        float Q[2][4];
        #pragma unroll
        for (int j = 0; j < 4; ++j) {
            Q[0][j] = lane_merge(q1[j][0], q1[j][2]);
            Q[1][j] = lane_merge(q1[j][1], q1[j][3]);
        }
        #pragma unroll
        for (int e = 0; e < 2; ++e) {             // cell 1
            float iv = rcp1p(Q[e][0]);
            float fv = rcp1p(Q[e][1]);
            float gr = rcp1p(Q[e][2]);
            float ov = rcp1p(Q[e][3]);
            float gl = __builtin_fmaf(gr, -2.0f * LAM, LAM);
            float c  = __builtin_fmaf(fv, cB[e], iv * gl);
            cB[e]    = c;
            float r2 = rcp1p(c);
            float h  = __builtin_fmaf(-2.0f, ov * r2, ov);
            Hw[e * U1S + 64] = f2bf(h);           // h_b(t)
        }
        wg_barrier();   // C
    }

    // epilogue: deferred FC for the final step
    if (wave == 0) {
        short8 a12 = *(const short8*)(Ar + 64);
        short8 a13 = *(const short8*)(Ar + 96);
        floatx4 so = {fcb, fcb, fcb, fcb};
        so = MFMA(a12, BF[0], so);
        so = MFMA(a13, BF[1], so);
        #pragma unroll
        for (int reg = 0; reg < 4; ++reg) {
            s_reg[reg] += so[reg] * DTC;
            if (quad < 2 && il < 8) {
                size_t o = ((size_t)(bb + 4 * quad + reg) * ns + (ns - 1)) * 8 + il;
                out[o] = s_reg[reg];
                res[o] = so[reg];
            }
        }
    }
}

extern "C" void kernel_launch(void* const* d_in, const int* in_sizes, int n_in,
                              void* d_out, int out_size, void* d_ws, size_t ws_size,
                              hipStream_t stream) {
    const float* x     = (const float*)d_in[0];
    const float* s0    = (const float*)d_in[1];
    const float* W_ih0 = (const float*)d_in[2];
    const float* W_hh0 = (const float*)d_in[3];
    const float* b_ih0 = (const float*)d_in[4];
    const float* b_hh0 = (const float*)d_in[5];
    const float* W_ih1 = (const float*)d_in[6];
    const float* W_hh1 = (const float*)d_in[7];
    const float* b_ih1 = (const float*)d_in[8];
    const float* b_hh1 = (const float*)d_in[9];
    const float* fc_W  = (const float*)d_in[10];
    const float* fc_b  = (const float*)d_in[11];
    const int*   nsp   = (const int*)d_in[12];
    (void)d_ws; (void)ws_size; (void)n_in; (void)out_size;
    int B = in_sizes[0] / 8;          // 4096
    dim3 grid(B / 8), block(256);     // 512 blocks -> 2 per CU, independent barriers
    hipLaunchKernelGGL(lstm_mfma, grid, block, 0, stream,
        x, s0, W_ih0, W_hh0, b_ih0, b_hh0, W_ih1, W_hh1, b_ih1, b_hh1,
        fc_W, fc_b, nsp, (float*)d_out, B);
}